// Round 8
// baseline (586.826 us; speedup 1.0000x reference)
//
#include <hip/hip_runtime.h>

typedef unsigned short ush;
typedef unsigned int uint32;
typedef __attribute__((ext_vector_type(8))) __bf16 bf16x8;
typedef __attribute__((ext_vector_type(4))) float f32x4;
typedef __attribute__((ext_vector_type(4))) int i32x4;
typedef __attribute__((ext_vector_type(16))) char c8x16;

#define NTHR 512
#define SENC 256
#define TDEC 512
#define HDIM 128
#define H8STR 144  // i8 h row stride (bytes)
#define XSTR 520   // x row stride (ush)

// defer kernel geometry: 512 blocks x 2 rows -> 2 blocks/CU (TLP overlap)
#define NBLK_DF 512
#define RBD 2
// fallback geometry (R6): 256 blocks x 4 rows
#define NBLK_FB 256
#define RBF 4
#define HSTR 144
#define PSTR 1024

#define WS_NEEDED ((size_t)NBLK_DF * TDEC * RBD * HDIM * 2)   // 128 MB

#define LOG2E  1.4426950408889634f
#define LOG2E2 2.8853900817779268f

__device__ __forceinline__ float bf2f(ush u){
  uint32 v = ((uint32)u) << 16;
  return __builtin_bit_cast(float, v);
}
__device__ __forceinline__ ush f2bf(float f){            // RNE via v_cvt
  return __builtin_bit_cast(ush, (__bf16)f);
}
__device__ __forceinline__ float lo16f(uint32 w){ return __builtin_bit_cast(float, w << 16); }
__device__ __forceinline__ float hi16f(uint32 w){ return __builtin_bit_cast(float, w & 0xFFFF0000u); }

__device__ __forceinline__ float loadf(const void* p, int i, bool f32){
  return f32 ? ((const float*)p)[i] : bf2f(((const ush*)p)[i]);
}
__device__ __forceinline__ f32x4 M1(bf16x8 a, bf16x8 b, f32x4 c){
  return __builtin_amdgcn_mfma_f32_16x16x32_bf16(a, b, c, 0, 0, 0);
}
__device__ __forceinline__ i32x4 MI(i32x4 a, i32x4 b, i32x4 c){
  return __builtin_amdgcn_mfma_i32_16x16x64_i8(a, b, c, 0, 0, 0);
}

// ===================== DEFER kernel: 512 blocks x 2 rows =====================
// i8 gate GEMM (mfma_i32_16x16x64_i8, folded decoder weights) + deferred pred.
// RB=2: A[m]=h[m>>3] (8x replication); acc[0]=gates[q>>1][n]; lanes with equal
// (q>>1,n) duplicate identical work -- benign. Per-wave MFMA count unchanged
// (8/step); grid 512 -> 2 independent blocks/CU (4 waves/SIMD), so one block's
// serial phases (ds round-trip, tail chain, barrier) overlap the other's pipe
// work. __launch_bounds__(512,4) caps VGPR at 128 for co-residency.
__global__ void __launch_bounds__(NTHR, 4)
lstm_defer(const void* __restrict__ xg,  const void* __restrict__ wih,
           const void* __restrict__ whh, const void* __restrict__ bih,
           const void* __restrict__ bhh, const void* __restrict__ wfc,
           const void* __restrict__ bfc, void* __restrict__ outg,
           void* __restrict__ ws)
{
  __shared__ __attribute__((aligned(16))) ush x_lds[RBD * XSTR];       // [row][t*2+c]
  __shared__ __attribute__((aligned(16))) char h8s[2][RBD * H8STR];    // i8 h
  __shared__ __attribute__((aligned(16))) ush pred_lds[RBD][TDEC * 2]; // [row][d*2+o]

  const int tid   = threadIdx.x;
  const int lane  = tid & 63;
  const int wv    = tid >> 6;
  const int n     = lane & 15;
  const int q     = lane >> 4;
  const int q8    = q * 8;
  const int q16   = q * 16;
  const int rq    = q >> 1;      // this lane's batch row (duplicated x2)
  const int gbase = wv << 4;
  const int blk   = blockIdx.x;

  // runtime storage-dtype detection (bf16 vs f32) from w_hh bit patterns
  const uint32* wp = (const uint32*)whh;
  int cnt = 0;
  #pragma unroll
  for (int i = 0; i < 64; ++i){
    uint32 e = (wp[i] >> 7) & 0xFFu;
    cnt += (e >= 90u && e <= 140u) ? 1 : 0;
  }
  const bool isf32 = (cnt < 40);

  for (int i = tid; i < 2 * RBD * H8STR; i += NTHR) ((char*)h8s)[i] = 0;

  // stage 2 encoder rows into LDS as bf16
  if (!isf32){
    if (tid < 128){
      int row = tid >> 6, c = (tid & 63) * 8;
      uint4 v = *reinterpret_cast<const uint4*>((const ush*)xg + (blk * RBD + row) * (SENC * 2) + c);
      *reinterpret_cast<uint4*>(&x_lds[row * XSTR + c]) = v;
    }
  } else {
    for (int i = tid; i < RBD * SENC * 2; i += NTHR){
      int row = i >> 9, c = i & 511;
      x_lds[row * XSTR + c] = f2bf(((const float*)xg)[(blk * RBD + row) * (SENC * 2) + c]);
    }
  }

  // ---- loop-invariant preloads + ENCODER weight quantization (per-col) ----
  float wih0v[4], wih1v[4], biasv[4], smulv[4];
  i32x4 ifr[4][2];   // [gate p][khalf]: B[k][g], k = kh*64 + q16 + j
  #pragma unroll
  for (int p = 0; p < 4; ++p){
    int g = p * 128 + gbase + n;
    biasv[p] = loadf(bih, g, isf32) + loadf(bhh, g, isf32);
    wih0v[p] = loadf(wih, g * 2 + 0, isf32);
    wih1v[p] = loadf(wih, g * 2 + 1, isf32);
    float w[2][16]; float m = 0.0f;
    #pragma unroll
    for (int kh = 0; kh < 2; ++kh){
      #pragma unroll
      for (int j = 0; j < 16; ++j){
        float v = loadf(whh, g * HDIM + kh * 64 + q16 + j, isf32);
        w[kh][j] = v; m = __builtin_fmaxf(m, __builtin_fabsf(v));
      }
    }
    m = __builtin_fmaxf(m, __shfl_xor(m, 16, 64));
    m = __builtin_fmaxf(m, __shfl_xor(m, 32, 64));
    m = __builtin_fmaxf(m, 1e-20f);
    float sinv = 127.0f / m;
    smulv[p] = m * (1.0f / (127.0f * 127.0f));
    #pragma unroll
    for (int kh = 0; kh < 2; ++kh){
      c8x16 c;
      #pragma unroll
      for (int j = 0; j < 16; ++j)
        c[j] = (char)(int)__builtin_rintf(w[kh][j] * sinv);
      ifr[p][kh] = __builtin_bit_cast(i32x4, c);
    }
  }

  float cc = 0.0f;
  const int a8row  = (n >> 3) * H8STR;       // A[m]=h[m>>3]
  const int h8wofs = rq * H8STR + gbase + n; // duplicate lanes write same addr
  // history: ws[blk][step][row(2)][col(128)], step stride 256 ush
  ush* hlane = (ush*)ws + (((size_t)blk) << 17) + rq * HDIM + gbase + n;
  const bool dohist = ((q & 1) == 0);        // dedupe global stores

  __syncthreads();

#define DLOADA8(RBUF) \
    const char* ha = &h8s[RBUF][a8row]; \
    i32x4 a80 = *reinterpret_cast<const i32x4*>(ha + q16); \
    i32x4 a81 = *reinterpret_cast<const i32x4*>(ha + 64 + q16);

#define DGATEMM8 \
    i32x4 G2 = MI(a80, ifr[2][0], IZ); \
    i32x4 G0 = MI(a80, ifr[0][0], IZ); \
    i32x4 G1 = MI(a80, ifr[1][0], IZ); \
    i32x4 G3 = MI(a80, ifr[3][0], IZ); \
    G2 = MI(a81, ifr[2][1], G2); \
    G0 = MI(a81, ifr[0][1], G0); \
    G1 = MI(a81, ifr[1][1], G1); \
    G3 = MI(a81, ifr[3][1], G3);

#define DTAIL8(WBUF, DOH, HS, BX0, BX1, BX2, BX3) \
    float g2 = __builtin_fmaf((float)G2[0], smulv[2], BX2); \
    float Eg = __builtin_amdgcn_exp2f(g2 * LOG2E2); \
    float g0 = __builtin_fmaf((float)G0[0], smulv[0], BX0); \
    float ei = __builtin_amdgcn_exp2f(-g0 * LOG2E); \
    float g1 = __builtin_fmaf((float)G1[0], smulv[1], BX1); \
    float ef = __builtin_amdgcn_exp2f(-g1 * LOG2E); \
    float g3 = __builtin_fmaf((float)G3[0], smulv[3], BX3); \
    float eo = __builtin_amdgcn_exp2f(-g3 * LOG2E); \
    float sitg = (Eg - 1.0f) * __builtin_amdgcn_rcpf((1.0f + ei) * (Eg + 1.0f)); \
    float sf = __builtin_amdgcn_rcpf(1.0f + ef); \
    cc = sf * cc + sitg; \
    float ccl = __builtin_amdgcn_fmed3f(cc, -20.0f, 20.0f); \
    float Ec = __builtin_amdgcn_exp2f(ccl * LOG2E2); \
    float hh = (Ec - 1.0f) * __builtin_amdgcn_rcpf((1.0f + eo) * (Ec + 1.0f)); \
    h8s[WBUF][h8wofs] = (char)(int)__builtin_rintf(hh * 127.0f); \
    if (DOH && dohist) hlane[(HS) * (RBD * HDIM)] = f2bf(hh);

#define DENCSTEP(RBUF, WBUF, T, DOH, HS) { \
    DLOADA8(RBUF) \
    uint32 xw = *reinterpret_cast<const uint32*>(&x_lds[rq * XSTR + (T) * 2]); \
    DGATEMM8 \
    float xa = lo16f(xw), xb = hi16f(xw); \
    float bx0 = biasv[0] + __builtin_fmaf(wih0v[0], xa, wih1v[0] * xb); \
    float bx1 = biasv[1] + __builtin_fmaf(wih0v[1], xa, wih1v[1] * xb); \
    float bx2 = biasv[2] + __builtin_fmaf(wih0v[2], xa, wih1v[2] * xb); \
    float bx3 = biasv[3] + __builtin_fmaf(wih0v[3], xa, wih1v[3] * xb); \
    DTAIL8(WBUF, DOH, HS, bx0, bx1, bx2, bx3) \
    __syncthreads(); \
  }

#define DDECSTEP(RBUF, WBUF, D) { \
    DLOADA8(RBUF) \
    DGATEMM8 \
    DTAIL8(WBUF, 1, (D) + 1, biasv[0], biasv[1], biasv[2], biasv[3]) \
    __syncthreads(); \
  }

  const i32x4 IZ = {0, 0, 0, 0};
  const f32x4 Z  = {0.0f, 0.0f, 0.0f, 0.0f};

  // ---------------- encoder: 256 steps + first decode cell ------------------
  #pragma unroll 1
  for (int s = 0; s < SENC; s += 2){
    DENCSTEP(0, 1, s, 0, 0)
    DENCSTEP(1, 0, s + 1, 0, 0)
  }
  DENCSTEP(0, 1, SENC - 1, 1, 0)   // inp0 = x[:,-1,:]; h -> hist step 0

  // ---- decoder weight fold + re-quantize ----------------------------------
  {
    float bfc0 = loadf(bfc, 0, isf32), bfc1 = loadf(bfc, 1, isf32);
    #pragma unroll
    for (int p = 0; p < 4; ++p){
      int g = p * 128 + gbase + n;
      biasv[p] = biasv[p] + wih0v[p] * bfc0 + wih1v[p] * bfc1;
      float w[2][16]; float m = 0.0f;
      #pragma unroll
      for (int kh = 0; kh < 2; ++kh){
        #pragma unroll
        for (int j = 0; j < 16; ++j){
          int k = kh * 64 + q16 + j;
          float v = loadf(whh, g * HDIM + k, isf32)
                  + wih0v[p] * loadf(wfc, k, isf32)
                  + wih1v[p] * loadf(wfc, HDIM + k, isf32);
          w[kh][j] = v; m = __builtin_fmaxf(m, __builtin_fabsf(v));
        }
      }
      m = __builtin_fmaxf(m, __shfl_xor(m, 16, 64));
      m = __builtin_fmaxf(m, __shfl_xor(m, 32, 64));
      m = __builtin_fmaxf(m, 1e-20f);
      float sinv = 127.0f / m;
      smulv[p] = m * (1.0f / (127.0f * 127.0f));
      #pragma unroll
      for (int kh = 0; kh < 2; ++kh){
        c8x16 c;
        #pragma unroll
        for (int j = 0; j < 16; ++j)
          c[j] = (char)(int)__builtin_rintf(w[kh][j] * sinv);
        ifr[p][kh] = __builtin_bit_cast(i32x4, c);
      }
    }
  }

  // ---------------- decoder: pure h-recurrence ------------------------------
  #pragma unroll 1
  for (int d = 0; d < TDEC - 2; d += 2){
    DDECSTEP(1, 0, d)
    DDECSTEP(0, 1, d + 1)
  }
  DDECSTEP(1, 0, TDEC - 2)   // d==510 -> hist step 511

  // ---- deferred pred: per-block GEMM over own history ----------------------
  asm volatile("s_waitcnt vmcnt(0)" ::: "memory");
  __syncthreads();

  bf16x8 wfe[4];
  #pragma unroll
  for (int kk = 0; kk < 4; ++kk)
    #pragma unroll
    for (int j = 0; j < 8; ++j)
      wfe[kk][j] = (__bf16)loadf(wfc, (n & 1) * HDIM + kk * 32 + q8 + j, isf32);
  f32x4 predCe;
  {
    float pb = loadf(bfc, n & 1, isf32);
    predCe[0] = pb; predCe[1] = pb; predCe[2] = pb; predCe[3] = pb;
  }
  const ush* hg = (const ush*)ws + (((size_t)blk) << 17);
  // M = 1024 (step*2+row), 64 tiles of 16; wave wv owns tiles wv*8..+7
  #pragma unroll 4
  for (int i = 0; i < 8; ++i){
    int t = wv * 8 + i;
    const ush* ar = hg + ((t * 16 + n) << 7) + q8;   // A[m=16t+n][k=q8+..]
    bf16x8 a0 = __builtin_bit_cast(bf16x8, *reinterpret_cast<const uint4*>(ar));
    bf16x8 a1 = __builtin_bit_cast(bf16x8, *reinterpret_cast<const uint4*>(ar + 32));
    bf16x8 a2 = __builtin_bit_cast(bf16x8, *reinterpret_cast<const uint4*>(ar + 64));
    bf16x8 a3 = __builtin_bit_cast(bf16x8, *reinterpret_cast<const uint4*>(ar + 96));
    f32x4 P = M1(a0, wfe[0], predCe);
    f32x4 Q = M1(a2, wfe[2], Z);
    P = M1(a1, wfe[1], P);
    Q = M1(a3, wfe[3], Q);
    #pragma unroll
    for (int r = 0; r < 4; ++r){
      int m = t * 16 + 4 * q + r;       // step = m>>1, row = m&1
      pred_lds[m & 1][((m >> 1) << 1) + (n & 1)] = f2bf(P[r] + Q[r]);
    }
  }
  __syncthreads();

  // bulk coalesced output write: 2 rows x 1024 ush per block
  if (!isf32){
    if (tid < 256){
      int row = tid >> 7, c = (tid & 127) * 8;
      uint4 v = *reinterpret_cast<const uint4*>(&pred_lds[row][c]);
      *reinterpret_cast<uint4*>((ush*)outg + (blk * RBD + row) * (TDEC * 2) + c) = v;
    }
  } else {
    for (int i = tid; i < RBD * TDEC * 2; i += NTHR){
      int row = i >> 10, c = i & 1023;
      ((float*)outg)[(blk * RBD + row) * (TDEC * 2) + c] = bf2f(pred_lds[row][c]);
    }
  }
}

// ===================== FALLBACK kernel: exact R6 (no workspace) ==============
__global__ void __launch_bounds__(NTHR, 2)
lstm_fb(const void* __restrict__ xg,  const void* __restrict__ wih,
        const void* __restrict__ whh, const void* __restrict__ bih,
        const void* __restrict__ bhh, const void* __restrict__ wfc,
        const void* __restrict__ bfc, void* __restrict__ outg)
{
  __shared__ __attribute__((aligned(16))) ush x_lds[RBF * XSTR];
  __shared__ __attribute__((aligned(16))) ush h_lds[2][RBF * HSTR];
  __shared__ __attribute__((aligned(16))) char h8s[2][RBF * H8STR];
  __shared__ __attribute__((aligned(16))) ush pred_lds[RBF][PSTR];
  __shared__ __attribute__((aligned(16))) float ppart[2][RBF][2][4];

  const int tid   = threadIdx.x;
  const int lane  = tid & 63;
  const int wv    = tid >> 6;
  const int n     = lane & 15;
  const int q     = lane >> 4;
  const int q8    = q * 8;
  const int q16   = q * 16;
  const int gbase = wv << 4;
  const int blk   = blockIdx.x;

  const uint32* wp = (const uint32*)whh;
  int cnt = 0;
  #pragma unroll
  for (int i = 0; i < 64; ++i){
    uint32 e = (wp[i] >> 7) & 0xFFu;
    cnt += (e >= 90u && e <= 140u) ? 1 : 0;
  }
  const bool isf32 = (cnt < 40);

  for (int i = tid; i < 2 * RBF * HSTR; i += NTHR) h_lds[0][i] = 0;
  for (int i = tid; i < 2 * RBF * H8STR; i += NTHR) ((char*)h8s)[i] = 0;

  if (!isf32){
    if (tid < 256){
      int row = tid >> 6, c = (tid & 63) * 8;
      uint4 v = *reinterpret_cast<const uint4*>((const ush*)xg + (blk * RBF + row) * (SENC * 2) + c);
      *reinterpret_cast<uint4*>(&x_lds[row * XSTR + c]) = v;
    }
  } else {
    for (int i = tid; i < RBF * SENC * 2; i += NTHR){
      int row = i >> 9, c = i & 511;
      x_lds[row * XSTR + c] = f2bf(((const float*)xg)[(blk * RBF + row) * (SENC * 2) + c]);
    }
  }

  float wih0v[4], wih1v[4], biasv[4], smulv[4];
  i32x4 ifr[4][2];
  #pragma unroll
  for (int p = 0; p < 4; ++p){
    int g = p * 128 + gbase + n;
    biasv[p] = loadf(bih, g, isf32) + loadf(bhh, g, isf32);
    wih0v[p] = loadf(wih, g * 2 + 0, isf32);
    wih1v[p] = loadf(wih, g * 2 + 1, isf32);
    float w[2][16]; float m = 0.0f;
    #pragma unroll
    for (int kh = 0; kh < 2; ++kh){
      #pragma unroll
      for (int j = 0; j < 16; ++j){
        float v = loadf(whh, g * HDIM + kh * 64 + q16 + j, isf32);
        w[kh][j] = v; m = __builtin_fmaxf(m, __builtin_fabsf(v));
      }
    }
    m = __builtin_fmaxf(m, __shfl_xor(m, 16, 64));
    m = __builtin_fmaxf(m, __shfl_xor(m, 32, 64));
    m = __builtin_fmaxf(m, 1e-20f);
    float sinv = 127.0f / m;
    smulv[p] = m * (1.0f / (127.0f * 127.0f));
    #pragma unroll
    for (int kh = 0; kh < 2; ++kh){
      c8x16 c;
      #pragma unroll
      for (int j = 0; j < 16; ++j)
        c[j] = (char)(int)__builtin_rintf(w[kh][j] * sinv);
      ifr[p][kh] = __builtin_bit_cast(i32x4, c);
    }
  }
  const bool ispred = (wv == 0) || (wv == 3) || (wv == 5) || (wv == 6);
  const bool issum  = (wv == 1);
  const int  pkk    = (wv == 0) ? 0 : (wv == 3) ? 1 : (wv == 5) ? 2 : 3;
  const int  pofs   = pkk * 32 + q8;
  bf16x8 wpfr;
  #pragma unroll
  for (int j = 0; j < 8; ++j)
    wpfr[j] = (__bf16)loadf(wfc, (n & 1) * HDIM + pkk * 32 + q8 + j, isf32);
  f32x4 predC;
  {
    float pb = (wv == 0) ? loadf(bfc, n & 1, isf32) : 0.0f;
    predC[0] = pb; predC[1] = pb; predC[2] = pb; predC[3] = pb;
  }

  float cc = 0.0f;
  const int arow   = (n >> 2) * HSTR;
  const int a8row  = (n >> 2) * H8STR;
  const int hwofs  = q * HSTR + gbase + n;
  const int h8wofs = q * H8STR + gbase + n;
  const f32x4 Z  = {0.0f, 0.0f, 0.0f, 0.0f};
  const i32x4 IZ = {0, 0, 0, 0};

  __syncthreads();

#define FLOADA8(RBUF) \
    const char* ha = &h8s[RBUF][a8row]; \
    i32x4 a80 = *reinterpret_cast<const i32x4*>(ha + q16); \
    i32x4 a81 = *reinterpret_cast<const i32x4*>(ha + 64 + q16);

#define FGATEMM8 \
    i32x4 G2 = MI(a80, ifr[2][0], IZ); \
    i32x4 G0 = MI(a80, ifr[0][0], IZ); \
    i32x4 G1 = MI(a80, ifr[1][0], IZ); \
    i32x4 G3 = MI(a80, ifr[3][0], IZ); \
    G2 = MI(a81, ifr[2][1], G2); \
    G0 = MI(a81, ifr[0][1], G0); \
    G1 = MI(a81, ifr[1][1], G1); \
    G3 = MI(a81, ifr[3][1], G3);

#define FTAIL8(WBUF, BX0, BX1, BX2, BX3) \
    float g2 = __builtin_fmaf((float)G2[0], smulv[2], BX2); \
    float Eg = __builtin_amdgcn_exp2f(g2 * LOG2E2); \
    float g0 = __builtin_fmaf((float)G0[0], smulv[0], BX0); \
    float ei = __builtin_amdgcn_exp2f(-g0 * LOG2E); \
    float g1 = __builtin_fmaf((float)G1[0], smulv[1], BX1); \
    float ef = __builtin_amdgcn_exp2f(-g1 * LOG2E); \
    float g3 = __builtin_fmaf((float)G3[0], smulv[3], BX3); \
    float eo = __builtin_amdgcn_exp2f(-g3 * LOG2E); \
    float sitg = (Eg - 1.0f) * __builtin_amdgcn_rcpf((1.0f + ei) * (Eg + 1.0f)); \
    float sf = __builtin_amdgcn_rcpf(1.0f + ef); \
    cc = sf * cc + sitg; \
    float ccl = __builtin_amdgcn_fmed3f(cc, -20.0f, 20.0f); \
    float Ec = __builtin_amdgcn_exp2f(ccl * LOG2E2); \
    float hh = (Ec - 1.0f) * __builtin_amdgcn_rcpf((1.0f + eo) * (Ec + 1.0f)); \
    h8s[WBUF][h8wofs] = (char)(int)__builtin_rintf(hh * 127.0f); \
    h_lds[WBUF][hwofs] = f2bf(hh);

#define FENCSTEP(RBUF, WBUF, T) { \
    FLOADA8(RBUF) \
    uint32 xw = *reinterpret_cast<const uint32*>(&x_lds[q * XSTR + (T) * 2]); \
    FGATEMM8 \
    float xa = lo16f(xw), xb = hi16f(xw); \
    float bx0 = biasv[0] + __builtin_fmaf(wih0v[0], xa, wih1v[0] * xb); \
    float bx1 = biasv[1] + __builtin_fmaf(wih0v[1], xa, wih1v[1] * xb); \
    float bx2 = biasv[2] + __builtin_fmaf(wih0v[2], xa, wih1v[2] * xb); \
    float bx3 = biasv[3] + __builtin_fmaf(wih0v[3], xa, wih1v[3] * xb); \
    FTAIL8(WBUF, bx0, bx1, bx2, bx3) \
    __syncthreads(); \
  }

#define FDECSTEP(RBUF, WBUF, D) { \
    FLOADA8(RBUF) \
    bf16x8 pfrag; \
    if (ispred) pfrag = *reinterpret_cast<const bf16x8*>(&h_lds[RBUF][arow] + pofs); \
    f32x4 pp; \
    if (issum && (D) > 0 && n < 2) \
      pp = *reinterpret_cast<const f32x4*>(&ppart[((D) - 1) & 1][q][n][0]); \
    FGATEMM8 \
    f32x4 PP; \
    if (ispred) PP = M1(pfrag, wpfr, predC); \
    if (issum && (D) > 0 && n < 2) \
      pred_lds[q][((D) - 1) * 2 + n] = f2bf(pp[0] + pp[1] + pp[2] + pp[3]); \
    if (ispred && n < 2) ppart[(D) & 1][q][n][pkk] = PP[0]; \
    FTAIL8(WBUF, biasv[0], biasv[1], biasv[2], biasv[3]) \
    __syncthreads(); \
  }

  #pragma unroll 1
  for (int s = 0; s < SENC; s += 2){
    FENCSTEP(0, 1, s)
    FENCSTEP(1, 0, s + 1)
  }
  FENCSTEP(0, 1, SENC - 1)

  {
    float bfc0 = loadf(bfc, 0, isf32), bfc1 = loadf(bfc, 1, isf32);
    #pragma unroll
    for (int p = 0; p < 4; ++p){
      int g = p * 128 + gbase + n;
      biasv[p] = biasv[p] + wih0v[p] * bfc0 + wih1v[p] * bfc1;
      float w[2][16]; float m = 0.0f;
      #pragma unroll
      for (int kh = 0; kh < 2; ++kh){
        #pragma unroll
        for (int j = 0; j < 16; ++j){
          int k = kh * 64 + q16 + j;
          float v = loadf(whh, g * HDIM + k, isf32)
                  + wih0v[p] * loadf(wfc, k, isf32)
                  + wih1v[p] * loadf(wfc, HDIM + k, isf32);
          w[kh][j] = v; m = __builtin_fmaxf(m, __builtin_fabsf(v));
        }
      }
      m = __builtin_fmaxf(m, __shfl_xor(m, 16, 64));
      m = __builtin_fmaxf(m, __shfl_xor(m, 32, 64));
      m = __builtin_fmaxf(m, 1e-20f);
      float sinv = 127.0f / m;
      smulv[p] = m * (1.0f / (127.0f * 127.0f));
      #pragma unroll
      for (int kh = 0; kh < 2; ++kh){
        c8x16 c;
        #pragma unroll
        for (int j = 0; j < 16; ++j)
          c[j] = (char)(int)__builtin_rintf(w[kh][j] * sinv);
        ifr[p][kh] = __builtin_bit_cast(i32x4, c);
      }
    }
  }

  #pragma unroll 1
  for (int d = 0; d < TDEC - 2; d += 2){
    FDECSTEP(1, 0, d)
    FDECSTEP(0, 1, d + 1)
  }
  FDECSTEP(1, 0, TDEC - 2)

  if (issum && n < 2){
    f32x4 pp = *reinterpret_cast<const f32x4*>(&ppart[0][q][n][0]);
    pred_lds[q][(TDEC - 2) * 2 + n] = f2bf(pp[0] + pp[1] + pp[2] + pp[3]);
  }
  if (wv == 0){
    const ush* hb = &h_lds[0][arow];
    bf16x8 af0 = *reinterpret_cast<const bf16x8*>(hb + q8);
    bf16x8 af2 = *reinterpret_cast<const bf16x8*>(hb + 64 + q8);
    bf16x8 af1 = *reinterpret_cast<const bf16x8*>(hb + 32 + q8);
    bf16x8 af3 = *reinterpret_cast<const bf16x8*>(hb + 96 + q8);
    bf16x8 wf0, wf1, wf2, wf3;
    #pragma unroll
    for (int j = 0; j < 8; ++j){
      wf0[j] = (__bf16)loadf(wfc, (n & 1) * HDIM +   0 + q8 + j, isf32);
      wf1[j] = (__bf16)loadf(wfc, (n & 1) * HDIM +  32 + q8 + j, isf32);
      wf2[j] = (__bf16)loadf(wfc, (n & 1) * HDIM +  64 + q8 + j, isf32);
      wf3[j] = (__bf16)loadf(wfc, (n & 1) * HDIM +  96 + q8 + j, isf32);
    }
    f32x4 P = M1(af0, wf0, predC);
    f32x4 Q = M1(af2, wf2, Z);
    P = M1(af1, wf1, P);
    Q = M1(af3, wf3, Q);
    if (n < 2)
      pred_lds[q][(TDEC - 1) * 2 + n] = f2bf(P[0] + Q[0]);
  }
  __syncthreads();

  if (!isf32){
    int row = tid >> 7, c = (tid & 127) * 8;
    uint4 v = *reinterpret_cast<const uint4*>(&pred_lds[row][c]);
    *reinterpret_cast<uint4*>((ush*)outg + (blk * RBF + row) * (TDEC * 2) + c) = v;
  } else {
    for (int i = tid; i < RBF * TDEC * 2; i += NTHR){
      int row = i >> 10, c = i & 1023;
      ((float*)outg)[(blk * RBF + row) * (TDEC * 2) + c] = bf2f(pred_lds[row][c]);
    }
  }
}

extern "C" void kernel_launch(void* const* d_in, const int* in_sizes, int n_in,
                              void* d_out, int out_size, void* d_ws, size_t ws_size,
                              hipStream_t stream) {
  const bool defer = (d_ws != nullptr) && (ws_size >= WS_NEEDED);
  if (defer){
    lstm_defer<<<dim3(NBLK_DF), dim3(NTHR), 0, stream>>>(
        d_in[0], d_in[1], d_in[2], d_in[3], d_in[4], d_in[5], d_in[6], d_out, d_ws);
  } else {
    lstm_fb<<<dim3(NBLK_FB), dim3(NTHR), 0, stream>>>(
        d_in[0], d_in[1], d_in[2], d_in[3], d_in[4], d_in[5], d_in[6], d_out);
  }
}

// Round 9
// 406.750 us; speedup vs baseline: 1.4427x; 1.4427x over previous
//
#include <hip/hip_runtime.h>

typedef unsigned short ush;
typedef unsigned int uint32;
typedef __attribute__((ext_vector_type(8))) __bf16 bf16x8;
typedef __attribute__((ext_vector_type(4))) float f32x4;
typedef __attribute__((ext_vector_type(4))) int i32x4;
typedef __attribute__((ext_vector_type(16))) char c8x16;

#define NBLK 256
#define RB   4     // batch rows per block
#define NTHR 512
#define SENC 256
#define TDEC 512
#define HDIM 128
#define HSTR 144   // bf16 h row stride (ush)
#define H8STR 144  // i8 h row stride (bytes)
#define XSTR 520   // x row stride (ush)
#define PSTR 1024  // pred row stride (ush)
#define HIST_USH_PER_BLK (TDEC * RB * HDIM)           // 262144 ush = 512 KB
#define WS_NEEDED ((size_t)NBLK * HIST_USH_PER_BLK * 2)

#define LOG2E  1.4426950408889634f
#define LOG2E2 2.8853900817779268f

__device__ __forceinline__ float bf2f(ush u){
  uint32 v = ((uint32)u) << 16;
  return __builtin_bit_cast(float, v);
}
__device__ __forceinline__ ush f2bf(float f){            // RNE via v_cvt
  return __builtin_bit_cast(ush, (__bf16)f);
}
__device__ __forceinline__ float lo16f(uint32 w){ return __builtin_bit_cast(float, w << 16); }
__device__ __forceinline__ float hi16f(uint32 w){ return __builtin_bit_cast(float, w & 0xFFFF0000u); }

__device__ __forceinline__ float loadf(const void* p, int i, bool f32){
  return f32 ? ((const float*)p)[i] : bf2f(((const ush*)p)[i]);
}
__device__ __forceinline__ f32x4 M1(bf16x8 a, bf16x8 b, f32x4 c){
  return __builtin_amdgcn_mfma_f32_16x16x32_bf16(a, b, c, 0, 0, 0);
}
__device__ __forceinline__ i32x4 MI(i32x4 a, i32x4 b, i32x4 c){
  return __builtin_amdgcn_mfma_i32_16x16x64_i8(a, b, c, 0, 0, 0);
}

// R9 = R7 (256 blocks x 4 rows, i8 gate GEMM, deferred pred) with the in-loop
// __syncthreads replaced by a LIGHTWEIGHT BARRIER: s_waitcnt lgkmcnt(0) +
// s_barrier + sched_barrier(0). __syncthreads drains vmcnt(0) before
// s_barrier, which put the per-step history global_store's L2-ack (~100-300cy)
// on the critical path in R7. The step's only cross-wave dependency is the
// i8 h LDS write (lgkm); history stores stay in flight and are drained ONCE
// (vmcnt(0)) before the deferred pred GEMM. sched_barrier(0) fences the
// next step's ds_read from being hoisted above the barrier (rule #18).
template<bool DEFER>
__global__ void __launch_bounds__(NTHR, 2)
lstm_kernel(const void* __restrict__ xg,  const void* __restrict__ wih,
            const void* __restrict__ whh, const void* __restrict__ bih,
            const void* __restrict__ bhh, const void* __restrict__ wfc,
            const void* __restrict__ bfc, void* __restrict__ outg,
            void* __restrict__ ws)
{
  __shared__ __attribute__((aligned(16))) ush x_lds[RB * XSTR];      // [row][t*2+c]
  __shared__ __attribute__((aligned(16))) ush h_lds[2][RB * HSTR];   // bf16 h (fallback pred path)
  __shared__ __attribute__((aligned(16))) char h8s[2][RB * H8STR];   // i8 h (gate path)
  __shared__ __attribute__((aligned(16))) ush pred_lds[RB][PSTR];    // [row][d*2+o]
  __shared__ __attribute__((aligned(16))) float ppart[2][RB][2][4];  // [buf][row][o][kk]

  constexpr bool DF = DEFER;

  const int tid   = threadIdx.x;
  const int lane  = tid & 63;
  const int wv    = tid >> 6;
  const int n     = lane & 15;   // MFMA col index within tile (= A-row m)
  const int q     = lane >> 4;   // quad; this lane's batch row
  const int q8    = q * 8;
  const int q16   = q * 16;
  const int gbase = wv << 4;
  const int blk   = blockIdx.x;

  // runtime storage-dtype detection (bf16 vs f32) from w_hh bit patterns
  const uint32* wp = (const uint32*)whh;
  int cnt = 0;
  #pragma unroll
  for (int i = 0; i < 64; ++i){
    uint32 e = (wp[i] >> 7) & 0xFFu;
    cnt += (e >= 90u && e <= 140u) ? 1 : 0;
  }
  const bool isf32 = (cnt < 40);

  for (int i = tid; i < 2 * RB * HSTR; i += NTHR) h_lds[0][i] = 0;   // both bufs
  for (int i = tid; i < 2 * RB * H8STR; i += NTHR) ((char*)h8s)[i] = 0;

  // stage this block's 4 encoder rows into LDS as bf16: [row][t*2+c]
  if (!isf32){
    if (tid < 256){
      int row = tid >> 6, c = (tid & 63) * 8;
      uint4 v = *reinterpret_cast<const uint4*>((const ush*)xg + (blk * RB + row) * (SENC * 2) + c);
      *reinterpret_cast<uint4*>(&x_lds[row * XSTR + c]) = v;
    }
  } else {
    for (int i = tid; i < RB * SENC * 2; i += NTHR){
      int row = i >> 9, c = i & 511;
      x_lds[row * XSTR + c] = f2bf(((const float*)xg)[(blk * RB + row) * (SENC * 2) + c]);
    }
  }

  // ---- loop-invariant preloads + ENCODER weight quantization (per-col) ----
  float wih0v[4], wih1v[4], biasv[4], smulv[4];
  i32x4 ifr[4][2];   // [gate p][khalf]: B[k][g], k = kh*64 + q16 + j
  #pragma unroll
  for (int p = 0; p < 4; ++p){
    int g = p * 128 + gbase + n;
    biasv[p] = loadf(bih, g, isf32) + loadf(bhh, g, isf32);
    wih0v[p] = loadf(wih, g * 2 + 0, isf32);
    wih1v[p] = loadf(wih, g * 2 + 1, isf32);
    float w[2][16]; float m = 0.0f;
    #pragma unroll
    for (int kh = 0; kh < 2; ++kh){
      #pragma unroll
      for (int j = 0; j < 16; ++j){
        float v = loadf(whh, g * HDIM + kh * 64 + q16 + j, isf32);
        w[kh][j] = v; m = __builtin_fmaxf(m, __builtin_fabsf(v));
      }
    }
    m = __builtin_fmaxf(m, __shfl_xor(m, 16, 64));   // reduce over q (k-cover)
    m = __builtin_fmaxf(m, __shfl_xor(m, 32, 64));
    m = __builtin_fmaxf(m, 1e-20f);
    float sinv = 127.0f / m;
    smulv[p] = m * (1.0f / (127.0f * 127.0f));
    #pragma unroll
    for (int kh = 0; kh < 2; ++kh){
      c8x16 c;
      #pragma unroll
      for (int j = 0; j < 16; ++j)
        c[j] = (char)(int)__builtin_rintf(w[kh][j] * sinv);
      ifr[p][kh] = __builtin_bit_cast(i32x4, c);
    }
  }
  // fallback pred partial setup: waves {0,3,5,6} own K-slices; wave 1 sums.
  const bool ispred = (wv == 0) || (wv == 3) || (wv == 5) || (wv == 6);
  const bool issum  = (wv == 1);
  const int  pkk    = (wv == 0) ? 0 : (wv == 3) ? 1 : (wv == 5) ? 2 : 3;
  const int  pofs   = pkk * 32 + q8;
  bf16x8 wpfr;   // B[k][n] = wfc[n&1][k], k = pkk*32+q*8+j (column-replicated)
  #pragma unroll
  for (int j = 0; j < 8; ++j)
    wpfr[j] = (__bf16)loadf(wfc, (n & 1) * HDIM + pkk * 32 + q8 + j, isf32);
  f32x4 predC;   // bias rides on the kk==0 partial (wave 0) [fallback]
  {
    float pb = (wv == 0) ? loadf(bfc, n & 1, isf32) : 0.0f;
    predC[0] = pb; predC[1] = pb; predC[2] = pb; predC[3] = pb;
  }

  float cc = 0.0f;                     // c-state for (row q, col gbase+n)
  const int arow   = (n >> 2) * HSTR;  // bf16 A-row base (fallback pred)
  const int a8row  = (n >> 2) * H8STR; // i8 A-row base
  const int hwofs  = q * HSTR + gbase + n;   // bf16 h-write offset
  const int h8wofs = q * H8STR + gbase + n;  // i8 h-write offset
  const f32x4 Z  = {0.0f, 0.0f, 0.0f, 0.0f};
  const i32x4 IZ = {0, 0, 0, 0};

  // per-lane history pointer: ws[blk][step][row=q][col=gbase+n], step stride 512 ush
  ush* hlane = (ush*)ws + (((size_t)blk) << 18) + q * HDIM + gbase + n;

  __syncthreads();

// lightweight step barrier (DEFER): order LDS only; leave global stores in
// flight. sched_barrier(0) prevents hoisting the next ds_read above it.
#define STEPBAR \
    if constexpr (DF){ \
      asm volatile("s_waitcnt lgkmcnt(0)" ::: "memory"); \
      __builtin_amdgcn_s_barrier(); \
      __builtin_amdgcn_sched_barrier(0); \
    } else { __syncthreads(); }

#define LOADA8(RBUF) \
    const char* ha = &h8s[RBUF][a8row]; \
    i32x4 a80 = *reinterpret_cast<const i32x4*>(ha + q16); \
    i32x4 a81 = *reinterpret_cast<const i32x4*>(ha + 64 + q16);

// g-gate (index 2) first: its chain retires earliest -> Eg starts early
#define GATEMM8 \
    i32x4 G2 = MI(a80, ifr[2][0], IZ); \
    i32x4 G0 = MI(a80, ifr[0][0], IZ); \
    i32x4 G1 = MI(a80, ifr[1][0], IZ); \
    i32x4 G3 = MI(a80, ifr[3][0], IZ); \
    G2 = MI(a81, ifr[2][1], G2); \
    G0 = MI(a81, ifr[0][1], G0); \
    G1 = MI(a81, ifr[1][1], G1); \
    G3 = MI(a81, ifr[3][1], G3);

// fused-rcp tail; gate = fma(float(acc), smul, bx).
// DEFER: i8 LDS write (critical) + fire-and-forget global bf16 history store.
// Fallback: dual LDS write (bf16 + i8).
#define TAIL8(WBUF, DOHIST, HS, BX0, BX1, BX2, BX3) \
    float g2 = __builtin_fmaf((float)G2[0], smulv[2], BX2); \
    float Eg = __builtin_amdgcn_exp2f(g2 * LOG2E2); \
    float g0 = __builtin_fmaf((float)G0[0], smulv[0], BX0); \
    float ei = __builtin_amdgcn_exp2f(-g0 * LOG2E); \
    float g1 = __builtin_fmaf((float)G1[0], smulv[1], BX1); \
    float ef = __builtin_amdgcn_exp2f(-g1 * LOG2E); \
    float g3 = __builtin_fmaf((float)G3[0], smulv[3], BX3); \
    float eo = __builtin_amdgcn_exp2f(-g3 * LOG2E); \
    float sitg = (Eg - 1.0f) * __builtin_amdgcn_rcpf((1.0f + ei) * (Eg + 1.0f)); \
    float sf = __builtin_amdgcn_rcpf(1.0f + ef); \
    cc = sf * cc + sitg; \
    float ccl = __builtin_amdgcn_fmed3f(cc, -20.0f, 20.0f); \
    float Ec = __builtin_amdgcn_exp2f(ccl * LOG2E2); \
    float hh = (Ec - 1.0f) * __builtin_amdgcn_rcpf((1.0f + eo) * (Ec + 1.0f)); \
    h8s[WBUF][h8wofs] = (char)(int)__builtin_rintf(hh * 127.0f); \
    if constexpr (DF){ if (DOHIST) hlane[(HS) * 512] = f2bf(hh); } \
    else { h_lds[WBUF][hwofs] = f2bf(hh); }

#define ENCSTEP(RBUF, WBUF, T, DOHIST, HS) { \
    LOADA8(RBUF) \
    uint32 xw = *reinterpret_cast<const uint32*>(&x_lds[q * XSTR + (T) * 2]); \
    GATEMM8 \
    /* x contribution folded into the bias term, in the MFMA-queue shadow */ \
    float xa = lo16f(xw), xb = hi16f(xw); \
    float bx0 = biasv[0] + __builtin_fmaf(wih0v[0], xa, wih1v[0] * xb); \
    float bx1 = biasv[1] + __builtin_fmaf(wih0v[1], xa, wih1v[1] * xb); \
    float bx2 = biasv[2] + __builtin_fmaf(wih0v[2], xa, wih1v[2] * xb); \
    float bx3 = biasv[3] + __builtin_fmaf(wih0v[3], xa, wih1v[3] * xb); \
    TAIL8(WBUF, DOHIST, HS, bx0, bx1, bx2, bx3) \
    STEPBAR \
  }

#define DECSTEP(RBUF, WBUF, D) { \
    LOADA8(RBUF) \
    if constexpr (!DF) { \
      bf16x8 pfrag; \
      if (ispred) pfrag = *reinterpret_cast<const bf16x8*>(&h_lds[RBUF][arow] + pofs); \
      f32x4 pp; \
      if (issum && (D) > 0 && n < 2) \
        pp = *reinterpret_cast<const f32x4*>(&ppart[((D) - 1) & 1][q][n][0]); \
      GATEMM8 \
      f32x4 PP; \
      if (ispred) PP = M1(pfrag, wpfr, predC); \
      if (issum && (D) > 0 && n < 2) \
        pred_lds[q][((D) - 1) * 2 + n] = f2bf(pp[0] + pp[1] + pp[2] + pp[3]); \
      if (ispred && n < 2) ppart[(D) & 1][q][n][pkk] = PP[0]; \
      TAIL8(WBUF, 0, 0, biasv[0], biasv[1], biasv[2], biasv[3]) \
    } else { \
      GATEMM8 \
      TAIL8(WBUF, 1, (D) + 1, biasv[0], biasv[1], biasv[2], biasv[3]) \
    } \
    STEPBAR \
  }

  // ---------------- encoder: 256 steps + first decode cell ------------------
  #pragma unroll 1
  for (int s = 0; s < SENC; s += 2){
    ENCSTEP(0, 1, s, 0, 0)
    ENCSTEP(1, 0, s + 1, 0, 0)
  }
  ENCSTEP(0, 1, SENC - 1, 1, 0)  // s==SENC: inp0 = x[:,-1,:]; h -> hist step 0

  // ---- decoder weight fold + re-quantize (registers/global only) ----------
  //   Whh'[g][k] = Whh[g][k] + wih0[g]*wfc[0][k] + wih1[g]*wfc[1][k]
  //   bias'[g]   = bias[g]   + wih0[g]*bfc[0]    + wih1[g]*bfc[1]
  {
    float bfc0 = loadf(bfc, 0, isf32), bfc1 = loadf(bfc, 1, isf32);
    #pragma unroll
    for (int p = 0; p < 4; ++p){
      int g = p * 128 + gbase + n;
      biasv[p] = biasv[p] + wih0v[p] * bfc0 + wih1v[p] * bfc1;
      float w[2][16]; float m = 0.0f;
      #pragma unroll
      for (int kh = 0; kh < 2; ++kh){
        #pragma unroll
        for (int j = 0; j < 16; ++j){
          int k = kh * 64 + q16 + j;
          float v = loadf(whh, g * HDIM + k, isf32)
                  + wih0v[p] * loadf(wfc, k, isf32)
                  + wih1v[p] * loadf(wfc, HDIM + k, isf32);
          w[kh][j] = v; m = __builtin_fmaxf(m, __builtin_fabsf(v));
        }
      }
      m = __builtin_fmaxf(m, __shfl_xor(m, 16, 64));
      m = __builtin_fmaxf(m, __shfl_xor(m, 32, 64));
      m = __builtin_fmaxf(m, 1e-20f);
      float sinv = 127.0f / m;
      smulv[p] = m * (1.0f / (127.0f * 127.0f));
      #pragma unroll
      for (int kh = 0; kh < 2; ++kh){
        c8x16 c;
        #pragma unroll
        for (int j = 0; j < 16; ++j)
          c[j] = (char)(int)__builtin_rintf(w[kh][j] * sinv);
        ifr[p][kh] = __builtin_bit_cast(i32x4, c);
      }
    }
  }

  // ---------------- decoder: pure h-recurrence (folded i8 weights) ----------
  #pragma unroll 1
  for (int d = 0; d < TDEC - 2; d += 2){
    DECSTEP(1, 0, d)
    DECSTEP(0, 1, d + 1)
  }
  DECSTEP(1, 0, TDEC - 2)   // d==510; its h -> hist step 511 (DEFER)

  if constexpr (DF){
    // ---- deferred pred: per-block GEMM over own history -------------------
    // single drain of ALL history stores, then block-wide visibility
    asm volatile("s_waitcnt vmcnt(0)" ::: "memory");
    __syncthreads();

    // column-replicated wfc frags + bias (all waves)
    bf16x8 wfe[4];
    #pragma unroll
    for (int kk = 0; kk < 4; ++kk)
      #pragma unroll
      for (int j = 0; j < 8; ++j)
        wfe[kk][j] = (__bf16)loadf(wfc, (n & 1) * HDIM + kk * 32 + q8 + j, isf32);
    f32x4 predCe;
    {
      float pb = loadf(bfc, n & 1, isf32);
      predCe[0] = pb; predCe[1] = pb; predCe[2] = pb; predCe[3] = pb;
    }
    const ush* hg = (const ush*)ws + (((size_t)blk) << 18);
    // M = 2048 (step*4+row), 128 tiles of 16; wave wv owns tiles wv*16..+15
    #pragma unroll 4
    for (int i = 0; i < 16; ++i){
      int t = wv * 16 + i;
      const ush* ar = hg + ((t * 16 + n) << 7) + q8;  // A[m=16t+n][k=q8+...]
      bf16x8 a0 = __builtin_bit_cast(bf16x8, *reinterpret_cast<const uint4*>(ar));
      bf16x8 a1 = __builtin_bit_cast(bf16x8, *reinterpret_cast<const uint4*>(ar + 32));
      bf16x8 a2 = __builtin_bit_cast(bf16x8, *reinterpret_cast<const uint4*>(ar + 64));
      bf16x8 a3 = __builtin_bit_cast(bf16x8, *reinterpret_cast<const uint4*>(ar + 96));
      f32x4 P = M1(a0, wfe[0], predCe);
      P = M1(a1, wfe[1], P);
      P = M1(a2, wfe[2], P);
      P = M1(a3, wfe[3], P);
      #pragma unroll
      for (int r = 0; r < 4; ++r){
        int m = t * 16 + 4 * q + r;     // (step = m>>2, row = m&3)
        pred_lds[m & 3][((m >> 2) << 1) + (n & 1)] = f2bf(P[r]);
      }
    }
  } else {
    // pending pred sum for d == TDEC-2 (buffer (TDEC-2)&1 == 0)
    if (issum && n < 2){
      f32x4 pp = *reinterpret_cast<const f32x4*>(&ppart[0][q][n][0]);
      pred_lds[q][(TDEC - 2) * 2 + n] = f2bf(pp[0] + pp[1] + pp[2] + pp[3]);
    }
    // epilogue: pred_511 from final h (buf0, bf16 copy), wave 0 full chain
    if (wv == 0){
      const ush* hb = &h_lds[0][arow];
      bf16x8 af0 = *reinterpret_cast<const bf16x8*>(hb + q8);
      bf16x8 af2 = *reinterpret_cast<const bf16x8*>(hb + 64 + q8);
      bf16x8 af1 = *reinterpret_cast<const bf16x8*>(hb + 32 + q8);
      bf16x8 af3 = *reinterpret_cast<const bf16x8*>(hb + 96 + q8);
      bf16x8 wf0, wf1, wf2, wf3;
      #pragma unroll
      for (int j = 0; j < 8; ++j){
        wf0[j] = (__bf16)loadf(wfc, (n & 1) * HDIM +   0 + q8 + j, isf32);
        wf1[j] = (__bf16)loadf(wfc, (n & 1) * HDIM +  32 + q8 + j, isf32);
        wf2[j] = (__bf16)loadf(wfc, (n & 1) * HDIM +  64 + q8 + j, isf32);
        wf3[j] = (__bf16)loadf(wfc, (n & 1) * HDIM +  96 + q8 + j, isf32);
      }
      f32x4 P = M1(af0, wf0, predC);
      f32x4 Q = M1(af2, wf2, Z);
      P = M1(af1, wf1, P);
      Q = M1(af3, wf3, Q);
      if (n < 2)
        pred_lds[q][(TDEC - 1) * 2 + n] = f2bf(P[0] + Q[0]);
    }
  }
  __syncthreads();

  // bulk coalesced output write: 4 rows x 1024 ush per block
  if (!isf32){
    int row = tid >> 7, c = (tid & 127) * 8;  // 512 threads x uint4
    uint4 v = *reinterpret_cast<const uint4*>(&pred_lds[row][c]);
    *reinterpret_cast<uint4*>((ush*)outg + (blk * RB + row) * (TDEC * 2) + c) = v;
  } else {
    for (int i = tid; i < RB * TDEC * 2; i += NTHR){
      int row = i >> 10, c = i & 1023;
      ((float*)outg)[(blk * RB + row) * (TDEC * 2) + c] = bf2f(pred_lds[row][c]);
    }
  }
}

extern "C" void kernel_launch(void* const* d_in, const int* in_sizes, int n_in,
                              void* d_out, int out_size, void* d_ws, size_t ws_size,
                              hipStream_t stream) {
  const bool defer = (d_ws != nullptr) && (ws_size >= WS_NEEDED);
  if (defer){
    lstm_kernel<true><<<dim3(NBLK), dim3(NTHR), 0, stream>>>(
        d_in[0], d_in[1], d_in[2], d_in[3], d_in[4], d_in[5], d_in[6], d_out, d_ws);
  } else {
    lstm_kernel<false><<<dim3(NBLK), dim3(NTHR), 0, stream>>>(
        d_in[0], d_in[1], d_in[2], d_in[3], d_in[4], d_in[5], d_in[6], d_out, d_ws);
  }
}

// Round 10
// 398.398 us; speedup vs baseline: 1.4730x; 1.0210x over previous
//
#include <hip/hip_runtime.h>

typedef unsigned short ush;
typedef unsigned int uint32;
typedef __attribute__((ext_vector_type(8))) __bf16 bf16x8;
typedef __attribute__((ext_vector_type(4))) float f32x4;
typedef __attribute__((ext_vector_type(4))) int i32x4;
typedef __attribute__((ext_vector_type(16))) char c8x16;

#define NBLK 256
#define RB   4     // batch rows per block
#define NTHR 512
#define SENC 256
#define TDEC 512
#define HDIM 128
#define HSTR 144   // bf16 h row stride (ush)
#define H8STR 144  // i8 h row stride (bytes)
#define XSTR 520   // x row stride (ush)
#define PSTR 1024  // pred row stride (ush)
#define HIST_USH_PER_BLK (TDEC * RB * HDIM)           // 262144 ush = 512 KB
#define WS_NEEDED ((size_t)NBLK * HIST_USH_PER_BLK * 2)

#define LOG2E  1.4426950408889634f
#define LOG2E2 2.8853900817779268f
#define INV127 0.007874015748031496f

__device__ __forceinline__ float bf2f(ush u){
  uint32 v = ((uint32)u) << 16;
  return __builtin_bit_cast(float, v);
}
__device__ __forceinline__ ush f2bf(float f){            // RNE via v_cvt
  return __builtin_bit_cast(ush, (__bf16)f);
}
__device__ __forceinline__ float lo16f(uint32 w){ return __builtin_bit_cast(float, w << 16); }
__device__ __forceinline__ float hi16f(uint32 w){ return __builtin_bit_cast(float, w & 0xFFFF0000u); }

__device__ __forceinline__ float loadf(const void* p, int i, bool f32){
  return f32 ? ((const float*)p)[i] : bf2f(((const ush*)p)[i]);
}
__device__ __forceinline__ f32x4 M1(bf16x8 a, bf16x8 b, f32x4 c){
  return __builtin_amdgcn_mfma_f32_16x16x32_bf16(a, b, c, 0, 0, 0);
}
__device__ __forceinline__ i32x4 MI(i32x4 a, i32x4 b, i32x4 c){
  return __builtin_amdgcn_mfma_i32_16x16x64_i8(a, b, c, 0, 0, 0);
}

// R10 = R9 (i8 gate GEMM, deferred pred, lightweight lgkm-only step barrier)
// with the serial tail shortened:
//  - exp2 coefficients FOLDED into the dequant scale and bias:
//      gate chain = cvt(G) -> fma(G, smulL, biasL) -> exp2   (no separate mul)
//      smulL[p] = coef[p]*smul[p], biasL[p] = coef[p]*bias[p],
//      coef = {-LOG2E, -LOG2E, +LOG2E2, -LOG2E} for {i,f,g,o}.
//      Encoder x-term uses wih0L/wih1L = coef*wih so bxL stays one fma pair.
//  - 127 folded into the h path: num = fma(Ec,127,-127); h127 = num*rcp(..);
//    i8 = rint(h127) (no extra mul); bf16 history h = h127*(1/127) AFTER the
//    critical ds_write.
template<bool DEFER>
__global__ void __launch_bounds__(NTHR, 2)
lstm_kernel(const void* __restrict__ xg,  const void* __restrict__ wih,
            const void* __restrict__ whh, const void* __restrict__ bih,
            const void* __restrict__ bhh, const void* __restrict__ wfc,
            const void* __restrict__ bfc, void* __restrict__ outg,
            void* __restrict__ ws)
{
  __shared__ __attribute__((aligned(16))) ush x_lds[RB * XSTR];      // [row][t*2+c]
  __shared__ __attribute__((aligned(16))) ush h_lds[2][RB * HSTR];   // bf16 h (fallback pred path)
  __shared__ __attribute__((aligned(16))) char h8s[2][RB * H8STR];   // i8 h (gate path)
  __shared__ __attribute__((aligned(16))) ush pred_lds[RB][PSTR];    // [row][d*2+o]
  __shared__ __attribute__((aligned(16))) float ppart[2][RB][2][4];  // [buf][row][o][kk]

  constexpr bool DF = DEFER;

  const int tid   = threadIdx.x;
  const int lane  = tid & 63;
  const int wv    = tid >> 6;
  const int n     = lane & 15;   // MFMA col index within tile (= A-row m)
  const int q     = lane >> 4;   // quad; this lane's batch row
  const int q8    = q * 8;
  const int q16   = q * 16;
  const int gbase = wv << 4;
  const int blk   = blockIdx.x;

  // runtime storage-dtype detection (bf16 vs f32) from w_hh bit patterns
  const uint32* wp = (const uint32*)whh;
  int cnt = 0;
  #pragma unroll
  for (int i = 0; i < 64; ++i){
    uint32 e = (wp[i] >> 7) & 0xFFu;
    cnt += (e >= 90u && e <= 140u) ? 1 : 0;
  }
  const bool isf32 = (cnt < 40);

  for (int i = tid; i < 2 * RB * HSTR; i += NTHR) h_lds[0][i] = 0;   // both bufs
  for (int i = tid; i < 2 * RB * H8STR; i += NTHR) ((char*)h8s)[i] = 0;

  // stage this block's 4 encoder rows into LDS as bf16: [row][t*2+c]
  if (!isf32){
    if (tid < 256){
      int row = tid >> 6, c = (tid & 63) * 8;
      uint4 v = *reinterpret_cast<const uint4*>((const ush*)xg + (blk * RB + row) * (SENC * 2) + c);
      *reinterpret_cast<uint4*>(&x_lds[row * XSTR + c]) = v;
    }
  } else {
    for (int i = tid; i < RB * SENC * 2; i += NTHR){
      int row = i >> 9, c = i & 511;
      x_lds[row * XSTR + c] = f2bf(((const float*)xg)[(blk * RB + row) * (SENC * 2) + c]);
    }
  }

  // gate->exp2 coefficient per gate: i,f,o use exp2(-g*LOG2E); g uses exp2(g*LOG2E2)
  const float coef0 = -LOG2E, coef1 = -LOG2E, coef2 = LOG2E2, coef3 = -LOG2E;

  // ---- loop-invariant preloads + ENCODER weight quantization (per-col) ----
  float wih0v[4], wih1v[4], biasv[4];        // normal domain (kept for the fold)
  float smulL[4], biasL[4], wih0L[4], wih1L[4];  // exp2-scaled domain
  i32x4 ifr[4][2];   // [gate p][khalf]: B[k][g], k = kh*64 + q16 + j
  #pragma unroll
  for (int p = 0; p < 4; ++p){
    const float cf = (p == 0) ? coef0 : (p == 1) ? coef1 : (p == 2) ? coef2 : coef3;
    int g = p * 128 + gbase + n;
    biasv[p] = loadf(bih, g, isf32) + loadf(bhh, g, isf32);
    wih0v[p] = loadf(wih, g * 2 + 0, isf32);
    wih1v[p] = loadf(wih, g * 2 + 1, isf32);
    float w[2][16]; float m = 0.0f;
    #pragma unroll
    for (int kh = 0; kh < 2; ++kh){
      #pragma unroll
      for (int j = 0; j < 16; ++j){
        float v = loadf(whh, g * HDIM + kh * 64 + q16 + j, isf32);
        w[kh][j] = v; m = __builtin_fmaxf(m, __builtin_fabsf(v));
      }
    }
    m = __builtin_fmaxf(m, __shfl_xor(m, 16, 64));   // reduce over q (k-cover)
    m = __builtin_fmaxf(m, __shfl_xor(m, 32, 64));
    m = __builtin_fmaxf(m, 1e-20f);
    float sinv = 127.0f / m;
    smulL[p] = cf * m * (1.0f / (127.0f * 127.0f));
    biasL[p] = cf * biasv[p];
    wih0L[p] = cf * wih0v[p];
    wih1L[p] = cf * wih1v[p];
    #pragma unroll
    for (int kh = 0; kh < 2; ++kh){
      c8x16 c;
      #pragma unroll
      for (int j = 0; j < 16; ++j)
        c[j] = (char)(int)__builtin_rintf(w[kh][j] * sinv);
      ifr[p][kh] = __builtin_bit_cast(i32x4, c);
    }
  }
  // fallback pred partial setup: waves {0,3,5,6} own K-slices; wave 1 sums.
  const bool ispred = (wv == 0) || (wv == 3) || (wv == 5) || (wv == 6);
  const bool issum  = (wv == 1);
  const int  pkk    = (wv == 0) ? 0 : (wv == 3) ? 1 : (wv == 5) ? 2 : 3;
  const int  pofs   = pkk * 32 + q8;
  bf16x8 wpfr;   // B[k][n] = wfc[n&1][k], k = pkk*32+q*8+j (column-replicated)
  #pragma unroll
  for (int j = 0; j < 8; ++j)
    wpfr[j] = (__bf16)loadf(wfc, (n & 1) * HDIM + pkk * 32 + q8 + j, isf32);
  f32x4 predC;   // bias rides on the kk==0 partial (wave 0) [fallback]
  {
    float pb = (wv == 0) ? loadf(bfc, n & 1, isf32) : 0.0f;
    predC[0] = pb; predC[1] = pb; predC[2] = pb; predC[3] = pb;
  }

  float cc = 0.0f;                     // c-state for (row q, col gbase+n)
  const int arow   = (n >> 2) * HSTR;  // bf16 A-row base (fallback pred)
  const int a8row  = (n >> 2) * H8STR; // i8 A-row base
  const int hwofs  = q * HSTR + gbase + n;   // bf16 h-write offset
  const int h8wofs = q * H8STR + gbase + n;  // i8 h-write offset
  const f32x4 Z  = {0.0f, 0.0f, 0.0f, 0.0f};
  const i32x4 IZ = {0, 0, 0, 0};

  // per-lane history pointer: ws[blk][step][row=q][col=gbase+n], step stride 512 ush
  ush* hlane = (ush*)ws + (((size_t)blk) << 18) + q * HDIM + gbase + n;

  __syncthreads();

// lightweight step barrier (DEFER): order LDS only; leave global stores in
// flight. sched_barrier(0) prevents hoisting the next ds_read above it.
#define STEPBAR \
    if constexpr (DF){ \
      asm volatile("s_waitcnt lgkmcnt(0)" ::: "memory"); \
      __builtin_amdgcn_s_barrier(); \
      __builtin_amdgcn_sched_barrier(0); \
    } else { __syncthreads(); }

#define LOADA8(RBUF) \
    const char* ha = &h8s[RBUF][a8row]; \
    i32x4 a80 = *reinterpret_cast<const i32x4*>(ha + q16); \
    i32x4 a81 = *reinterpret_cast<const i32x4*>(ha + 64 + q16);

// g-gate (index 2) first: its chain retires earliest -> Eg starts early
#define GATEMM8 \
    i32x4 G2 = MI(a80, ifr[2][0], IZ); \
    i32x4 G0 = MI(a80, ifr[0][0], IZ); \
    i32x4 G1 = MI(a80, ifr[1][0], IZ); \
    i32x4 G3 = MI(a80, ifr[3][0], IZ); \
    G2 = MI(a81, ifr[2][1], G2); \
    G0 = MI(a81, ifr[0][1], G0); \
    G1 = MI(a81, ifr[1][1], G1); \
    G3 = MI(a81, ifr[3][1], G3);

// scaled-domain tail: e = exp2(fma(cvt(G), smulL, BXL)) per gate (no mul on
// chain); 127 folded into the h path. i8 ds_write first (critical); history /
// fallback bf16 write after.
#define TAIL8(WBUF, DOHIST, HS, BX0L, BX1L, BX2L, BX3L) \
    float Eg = __builtin_amdgcn_exp2f(__builtin_fmaf((float)G2[0], smulL[2], BX2L)); \
    float ei = __builtin_amdgcn_exp2f(__builtin_fmaf((float)G0[0], smulL[0], BX0L)); \
    float ef = __builtin_amdgcn_exp2f(__builtin_fmaf((float)G1[0], smulL[1], BX1L)); \
    float eo = __builtin_amdgcn_exp2f(__builtin_fmaf((float)G3[0], smulL[3], BX3L)); \
    float sitg = (Eg - 1.0f) * __builtin_amdgcn_rcpf((1.0f + ei) * (Eg + 1.0f)); \
    float sf = __builtin_amdgcn_rcpf(1.0f + ef); \
    cc = __builtin_fmaf(sf, cc, sitg); \
    float ccl = __builtin_amdgcn_fmed3f(cc, -20.0f, 20.0f); \
    float Ec = __builtin_amdgcn_exp2f(ccl * LOG2E2); \
    float num = __builtin_fmaf(Ec, 127.0f, -127.0f); \
    float h127 = num * __builtin_amdgcn_rcpf((1.0f + eo) * (Ec + 1.0f)); \
    h8s[WBUF][h8wofs] = (char)(int)__builtin_rintf(h127); \
    if constexpr (DF){ if (DOHIST) hlane[(HS) * 512] = f2bf(h127 * INV127); } \
    else { h_lds[WBUF][hwofs] = f2bf(h127 * INV127); }

#define ENCSTEP(RBUF, WBUF, T, DOHIST, HS) { \
    LOADA8(RBUF) \
    uint32 xw = *reinterpret_cast<const uint32*>(&x_lds[q * XSTR + (T) * 2]); \
    GATEMM8 \
    /* x contribution in the scaled domain, in the MFMA-queue shadow */ \
    float xa = lo16f(xw), xb = hi16f(xw); \
    float bx0 = __builtin_fmaf(wih0L[0], xa, __builtin_fmaf(wih1L[0], xb, biasL[0])); \
    float bx1 = __builtin_fmaf(wih0L[1], xa, __builtin_fmaf(wih1L[1], xb, biasL[1])); \
    float bx2 = __builtin_fmaf(wih0L[2], xa, __builtin_fmaf(wih1L[2], xb, biasL[2])); \
    float bx3 = __builtin_fmaf(wih0L[3], xa, __builtin_fmaf(wih1L[3], xb, biasL[3])); \
    TAIL8(WBUF, DOHIST, HS, bx0, bx1, bx2, bx3) \
    STEPBAR \
  }

#define DECSTEP(RBUF, WBUF, D) { \
    LOADA8(RBUF) \
    if constexpr (!DF) { \
      bf16x8 pfrag; \
      if (ispred) pfrag = *reinterpret_cast<const bf16x8*>(&h_lds[RBUF][arow] + pofs); \
      f32x4 pp; \
      if (issum && (D) > 0 && n < 2) \
        pp = *reinterpret_cast<const f32x4*>(&ppart[((D) - 1) & 1][q][n][0]); \
      GATEMM8 \
      f32x4 PP; \
      if (ispred) PP = M1(pfrag, wpfr, predC); \
      if (issum && (D) > 0 && n < 2) \
        pred_lds[q][((D) - 1) * 2 + n] = f2bf(pp[0] + pp[1] + pp[2] + pp[3]); \
      if (ispred && n < 2) ppart[(D) & 1][q][n][pkk] = PP[0]; \
      TAIL8(WBUF, 0, 0, biasL[0], biasL[1], biasL[2], biasL[3]) \
    } else { \
      GATEMM8 \
      TAIL8(WBUF, 1, (D) + 1, biasL[0], biasL[1], biasL[2], biasL[3]) \
    } \
    STEPBAR \
  }

  // ---------------- encoder: 256 steps + first decode cell ------------------
  #pragma unroll 1
  for (int s = 0; s < SENC; s += 2){
    ENCSTEP(0, 1, s, 0, 0)
    ENCSTEP(1, 0, s + 1, 0, 0)
  }
  ENCSTEP(0, 1, SENC - 1, 1, 0)  // s==SENC: inp0 = x[:,-1,:]; h -> hist step 0

  // ---- decoder weight fold + re-quantize (registers/global only) ----------
  //   Whh'[g][k] = Whh[g][k] + wih0[g]*wfc[0][k] + wih1[g]*wfc[1][k]
  //   bias'[g]   = bias[g]   + wih0[g]*bfc[0]    + wih1[g]*bfc[1]
  {
    float bfc0 = loadf(bfc, 0, isf32), bfc1 = loadf(bfc, 1, isf32);
    #pragma unroll
    for (int p = 0; p < 4; ++p){
      const float cf = (p == 0) ? coef0 : (p == 1) ? coef1 : (p == 2) ? coef2 : coef3;
      int g = p * 128 + gbase + n;
      biasv[p] = biasv[p] + wih0v[p] * bfc0 + wih1v[p] * bfc1;
      float w[2][16]; float m = 0.0f;
      #pragma unroll
      for (int kh = 0; kh < 2; ++kh){
        #pragma unroll
        for (int j = 0; j < 16; ++j){
          int k = kh * 64 + q16 + j;
          float v = loadf(whh, g * HDIM + k, isf32)
                  + wih0v[p] * loadf(wfc, k, isf32)
                  + wih1v[p] * loadf(wfc, HDIM + k, isf32);
          w[kh][j] = v; m = __builtin_fmaxf(m, __builtin_fabsf(v));
        }
      }
      m = __builtin_fmaxf(m, __shfl_xor(m, 16, 64));
      m = __builtin_fmaxf(m, __shfl_xor(m, 32, 64));
      m = __builtin_fmaxf(m, 1e-20f);
      float sinv = 127.0f / m;
      smulL[p] = cf * m * (1.0f / (127.0f * 127.0f));
      biasL[p] = cf * biasv[p];
      #pragma unroll
      for (int kh = 0; kh < 2; ++kh){
        c8x16 c;
        #pragma unroll
        for (int j = 0; j < 16; ++j)
          c[j] = (char)(int)__builtin_rintf(w[kh][j] * sinv);
        ifr[p][kh] = __builtin_bit_cast(i32x4, c);
      }
    }
  }

  // ---------------- decoder: pure h-recurrence (folded i8 weights) ----------
  #pragma unroll 1
  for (int d = 0; d < TDEC - 2; d += 2){
    DECSTEP(1, 0, d)
    DECSTEP(0, 1, d + 1)
  }
  DECSTEP(1, 0, TDEC - 2)   // d==510; its h -> hist step 511 (DEFER)

  if constexpr (DF){
    // ---- deferred pred: per-block GEMM over own history -------------------
    // single drain of ALL history stores, then block-wide visibility
    asm volatile("s_waitcnt vmcnt(0)" ::: "memory");
    __syncthreads();

    // column-replicated wfc frags + bias (all waves)
    bf16x8 wfe[4];
    #pragma unroll
    for (int kk = 0; kk < 4; ++kk)
      #pragma unroll
      for (int j = 0; j < 8; ++j)
        wfe[kk][j] = (__bf16)loadf(wfc, (n & 1) * HDIM + kk * 32 + q8 + j, isf32);
    f32x4 predCe;
    {
      float pb = loadf(bfc, n & 1, isf32);
      predCe[0] = pb; predCe[1] = pb; predCe[2] = pb; predCe[3] = pb;
    }
    const ush* hg = (const ush*)ws + (((size_t)blk) << 18);
    // M = 2048 (step*4+row), 128 tiles of 16; wave wv owns tiles wv*16..+15
    #pragma unroll 4
    for (int i = 0; i < 16; ++i){
      int t = wv * 16 + i;
      const ush* ar = hg + ((t * 16 + n) << 7) + q8;  // A[m=16t+n][k=q8+...]
      bf16x8 a0 = __builtin_bit_cast(bf16x8, *reinterpret_cast<const uint4*>(ar));
      bf16x8 a1 = __builtin_bit_cast(bf16x8, *reinterpret_cast<const uint4*>(ar + 32));
      bf16x8 a2 = __builtin_bit_cast(bf16x8, *reinterpret_cast<const uint4*>(ar + 64));
      bf16x8 a3 = __builtin_bit_cast(bf16x8, *reinterpret_cast<const uint4*>(ar + 96));
      f32x4 P = M1(a0, wfe[0], predCe);
      P = M1(a1, wfe[1], P);
      P = M1(a2, wfe[2], P);
      P = M1(a3, wfe[3], P);
      #pragma unroll
      for (int r = 0; r < 4; ++r){
        int m = t * 16 + 4 * q + r;     // (step = m>>2, row = m&3)
        pred_lds[m & 3][((m >> 2) << 1) + (n & 1)] = f2bf(P[r]);
      }
    }
  } else {
    // pending pred sum for d == TDEC-2 (buffer (TDEC-2)&1 == 0)
    if (issum && n < 2){
      f32x4 pp = *reinterpret_cast<const f32x4*>(&ppart[0][q][n][0]);
      pred_lds[q][(TDEC - 2) * 2 + n] = f2bf(pp[0] + pp[1] + pp[2] + pp[3]);
    }
    // epilogue: pred_511 from final h (buf0, bf16 copy), wave 0 full chain
    if (wv == 0){
      const ush* hb = &h_lds[0][arow];
      bf16x8 af0 = *reinterpret_cast<const bf16x8*>(hb + q8);
      bf16x8 af2 = *reinterpret_cast<const bf16x8*>(hb + 64 + q8);
      bf16x8 af1 = *reinterpret_cast<const bf16x8*>(hb + 32 + q8);
      bf16x8 af3 = *reinterpret_cast<const bf16x8*>(hb + 96 + q8);
      bf16x8 wf0, wf1, wf2, wf3;
      #pragma unroll
      for (int j = 0; j < 8; ++j){
        wf0[j] = (__bf16)loadf(wfc, (n & 1) * HDIM +   0 + q8 + j, isf32);
        wf1[j] = (__bf16)loadf(wfc, (n & 1) * HDIM +  32 + q8 + j, isf32);
        wf2[j] = (__bf16)loadf(wfc, (n & 1) * HDIM +  64 + q8 + j, isf32);
        wf3[j] = (__bf16)loadf(wfc, (n & 1) * HDIM +  96 + q8 + j, isf32);
      }
      f32x4 P = M1(af0, wf0, predC);
      f32x4 Q = M1(af2, wf2, Z);
      P = M1(af1, wf1, P);
      Q = M1(af3, wf3, Q);
      if (n < 2)
        pred_lds[q][(TDEC - 1) * 2 + n] = f2bf(P[0] + Q[0]);
    }
  }
  __syncthreads();

  // bulk coalesced output write: 4 rows x 1024 ush per block
  if (!isf32){
    int row = tid >> 7, c = (tid & 127) * 8;  // 512 threads x uint4
    uint4 v = *reinterpret_cast<const uint4*>(&pred_lds[row][c]);
    *reinterpret_cast<uint4*>((ush*)outg + (blk * RB + row) * (TDEC * 2) + c) = v;
  } else {
    for (int i = tid; i < RB * TDEC * 2; i += NTHR){
      int row = i >> 10, c = i & 1023;
      ((float*)outg)[(blk * RB + row) * (TDEC * 2) + c] = bf2f(pred_lds[row][c]);
    }
  }
}

extern "C" void kernel_launch(void* const* d_in, const int* in_sizes, int n_in,
                              void* d_out, int out_size, void* d_ws, size_t ws_size,
                              hipStream_t stream) {
  const bool defer = (d_ws != nullptr) && (ws_size >= WS_NEEDED);
  if (defer){
    lstm_kernel<true><<<dim3(NBLK), dim3(NTHR), 0, stream>>>(
        d_in[0], d_in[1], d_in[2], d_in[3], d_in[4], d_in[5], d_in[6], d_out, d_ws);
  } else {
    lstm_kernel<false><<<dim3(NBLK), dim3(NTHR), 0, stream>>>(
        d_in[0], d_in[1], d_in[2], d_in[3], d_in[4], d_in[5], d_in[6], d_out, d_ws);
  }
}

// Round 12
// 394.753 us; speedup vs baseline: 1.4866x; 1.0092x over previous
//
#include <hip/hip_runtime.h>

typedef unsigned short ush;
typedef unsigned int uint32;
typedef __attribute__((ext_vector_type(8))) __bf16 bf16x8;
typedef __attribute__((ext_vector_type(4))) float f32x4;
typedef __attribute__((ext_vector_type(4))) int i32x4;
typedef __attribute__((ext_vector_type(16))) char c8x16;

#define NBLK 256
#define RB   4     // batch rows per block
#define NTHR 512
#define SENC 256
#define TDEC 512
#define HDIM 128
#define HSTR 144   // bf16 h row stride (ush)
#define H8STR 144  // i8 h row stride (bytes)
#define XSTR 520   // x row stride (ush)
#define PSTR 1024  // pred row stride (ush)
#define HIST_USH_PER_BLK (TDEC * RB * HDIM)           // 262144 ush = 512 KB
#define WS_NEEDED ((size_t)NBLK * HIST_USH_PER_BLK * 2)

#define LOG2E  1.4426950408889634f
#define LOG2E2 2.8853900817779268f
#define INV127 0.007874015748031496f

__device__ __forceinline__ float bf2f(ush u){
  uint32 v = ((uint32)u) << 16;
  return __builtin_bit_cast(float, v);
}
__device__ __forceinline__ ush f2bf(float f){            // RNE via v_cvt
  return __builtin_bit_cast(ush, (__bf16)f);
}
__device__ __forceinline__ float lo16f(uint32 w){ return __builtin_bit_cast(float, w << 16); }
__device__ __forceinline__ float hi16f(uint32 w){ return __builtin_bit_cast(float, w & 0xFFFF0000u); }

__device__ __forceinline__ float loadf(const void* p, int i, bool f32){
  return f32 ? ((const float*)p)[i] : bf2f(((const ush*)p)[i]);
}
__device__ __forceinline__ f32x4 M1(bf16x8 a, bf16x8 b, f32x4 c){
  return __builtin_amdgcn_mfma_f32_16x16x32_bf16(a, b, c, 0, 0, 0);
}
__device__ __forceinline__ i32x4 MI(i32x4 a, i32x4 b, i32x4 c){
  return __builtin_amdgcn_mfma_i32_16x16x64_i8(a, b, c, 0, 0, 0);
}

// R11 = R10 (i8 gate GEMM, deferred pred, lgkm-only step barrier, exp2-scaled
// dequant) with the tail reworked:
//  - SINGLE-RCP cc update: cc/F + (Eg-1)/P  ==  [cc*P + (Eg-1)*F] * rcp(F*P)
//    (F = 1+ef, P = (1+ei)(Eg+1)) -- one v_rcp instead of two per step.
//  - cc kept PERMANENTLY scaled by LOG2E2 (cc2 = L2*cc): the h-chain mul
//    before exp2 disappears; L2 folds into T = fma(Eg, F*L2, -F*L2) off-chain.
//    tanh-arg clamp at +-57.7 (= 20*L2); cc2 itself stays unclamped (exact).
//  - decoder unroll x4; history stores use one base per 4-step group with
//    immediate-offset folding (1024B strides fit the 13-bit offset field).
template<bool DEFER>
__global__ void __launch_bounds__(NTHR, 2)
lstm_kernel(const void* __restrict__ xg,  const void* __restrict__ wih,
            const void* __restrict__ whh, const void* __restrict__ bih,
            const void* __restrict__ bhh, const void* __restrict__ wfc,
            const void* __restrict__ bfc, void* __restrict__ outg,
            void* __restrict__ ws)
{
  __shared__ __attribute__((aligned(16))) ush x_lds[RB * XSTR];      // [row][t*2+c]
  __shared__ __attribute__((aligned(16))) ush h_lds[2][RB * HSTR];   // bf16 h (fallback pred path)
  __shared__ __attribute__((aligned(16))) char h8s[2][RB * H8STR];   // i8 h (gate path)
  __shared__ __attribute__((aligned(16))) ush pred_lds[RB][PSTR];    // [row][d*2+o]
  __shared__ __attribute__((aligned(16))) float ppart[2][RB][2][4];  // [buf][row][o][kk]

  constexpr bool DF = DEFER;

  const int tid   = threadIdx.x;
  const int lane  = tid & 63;
  const int wv    = tid >> 6;
  const int n     = lane & 15;   // MFMA col index within tile (= A-row m)
  const int q     = lane >> 4;   // quad; this lane's batch row
  const int q8    = q * 8;
  const int q16   = q * 16;
  const int gbase = wv << 4;
  const int blk   = blockIdx.x;

  // runtime storage-dtype detection (bf16 vs f32) from w_hh bit patterns
  const uint32* wp = (const uint32*)whh;
  int cnt = 0;
  #pragma unroll
  for (int i = 0; i < 64; ++i){
    uint32 e = (wp[i] >> 7) & 0xFFu;
    cnt += (e >= 90u && e <= 140u) ? 1 : 0;
  }
  const bool isf32 = (cnt < 40);

  for (int i = tid; i < 2 * RB * HSTR; i += NTHR) h_lds[0][i] = 0;   // both bufs
  for (int i = tid; i < 2 * RB * H8STR; i += NTHR) ((char*)h8s)[i] = 0;

  // stage this block's 4 encoder rows into LDS as bf16: [row][t*2+c]
  if (!isf32){
    if (tid < 256){
      int row = tid >> 6, c = (tid & 63) * 8;
      uint4 v = *reinterpret_cast<const uint4*>((const ush*)xg + (blk * RB + row) * (SENC * 2) + c);
      *reinterpret_cast<uint4*>(&x_lds[row * XSTR + c]) = v;
    }
  } else {
    for (int i = tid; i < RB * SENC * 2; i += NTHR){
      int row = i >> 9, c = i & 511;
      x_lds[row * XSTR + c] = f2bf(((const float*)xg)[(blk * RB + row) * (SENC * 2) + c]);
    }
  }

  // gate->exp2 coefficient per gate: i,f,o use exp2(-g*LOG2E); g uses exp2(g*LOG2E2)
  const float coef0 = -LOG2E, coef1 = -LOG2E, coef2 = LOG2E2, coef3 = -LOG2E;

  // ---- loop-invariant preloads + ENCODER weight quantization (per-col) ----
  float wih0v[4], wih1v[4], biasv[4];        // normal domain (kept for the fold)
  float smulL[4], biasL[4], wih0L[4], wih1L[4];  // exp2-scaled domain
  i32x4 ifr[4][2];   // [gate p][khalf]: B[k][g], k = kh*64 + q16 + j
  #pragma unroll
  for (int p = 0; p < 4; ++p){
    const float cf = (p == 0) ? coef0 : (p == 1) ? coef1 : (p == 2) ? coef2 : coef3;
    int g = p * 128 + gbase + n;
    biasv[p] = loadf(bih, g, isf32) + loadf(bhh, g, isf32);
    wih0v[p] = loadf(wih, g * 2 + 0, isf32);
    wih1v[p] = loadf(wih, g * 2 + 1, isf32);
    float w[2][16]; float m = 0.0f;
    #pragma unroll
    for (int kh = 0; kh < 2; ++kh){
      #pragma unroll
      for (int j = 0; j < 16; ++j){
        float v = loadf(whh, g * HDIM + kh * 64 + q16 + j, isf32);
        w[kh][j] = v; m = __builtin_fmaxf(m, __builtin_fabsf(v));
      }
    }
    m = __builtin_fmaxf(m, __shfl_xor(m, 16, 64));   // reduce over q (k-cover)
    m = __builtin_fmaxf(m, __shfl_xor(m, 32, 64));
    m = __builtin_fmaxf(m, 1e-20f);
    float sinv = 127.0f / m;
    smulL[p] = cf * m * (1.0f / (127.0f * 127.0f));
    biasL[p] = cf * biasv[p];
    wih0L[p] = cf * wih0v[p];
    wih1L[p] = cf * wih1v[p];
    #pragma unroll
    for (int kh = 0; kh < 2; ++kh){
      c8x16 c;
      #pragma unroll
      for (int j = 0; j < 16; ++j)
        c[j] = (char)(int)__builtin_rintf(w[kh][j] * sinv);
      ifr[p][kh] = __builtin_bit_cast(i32x4, c);
    }
  }
  // fallback pred partial setup: waves {0,3,5,6} own K-slices; wave 1 sums.
  const bool ispred = (wv == 0) || (wv == 3) || (wv == 5) || (wv == 6);
  const bool issum  = (wv == 1);
  const int  pkk    = (wv == 0) ? 0 : (wv == 3) ? 1 : (wv == 5) ? 2 : 3;
  const int  pofs   = pkk * 32 + q8;
  bf16x8 wpfr;   // B[k][n] = wfc[n&1][k], k = pkk*32+q*8+j (column-replicated)
  #pragma unroll
  for (int j = 0; j < 8; ++j)
    wpfr[j] = (__bf16)loadf(wfc, (n & 1) * HDIM + pkk * 32 + q8 + j, isf32);
  f32x4 predC;   // bias rides on the kk==0 partial (wave 0) [fallback]
  {
    float pb = (wv == 0) ? loadf(bfc, n & 1, isf32) : 0.0f;
    predC[0] = pb; predC[1] = pb; predC[2] = pb; predC[3] = pb;
  }

  float cc2 = 0.0f;                    // LOG2E2-scaled c-state for (row q, col gbase+n)
  const int arow   = (n >> 2) * HSTR;  // bf16 A-row base (fallback pred)
  const int a8row  = (n >> 2) * H8STR; // i8 A-row base
  const int hwofs  = q * HSTR + gbase + n;   // bf16 h-write offset
  const int h8wofs = q * H8STR + gbase + n;  // i8 h-write offset
  const f32x4 Z  = {0.0f, 0.0f, 0.0f, 0.0f};
  const i32x4 IZ = {0, 0, 0, 0};

  // per-lane history pointer: ws[blk][step][row=q][col=gbase+n], step stride 512 ush
  ush* hlane = (ush*)ws + (((size_t)blk) << 18) + q * HDIM + gbase + n;

  __syncthreads();

// lightweight step barrier (DEFER): order LDS only; leave global stores in
// flight. sched_barrier(0) prevents hoisting the next ds_read above it.
#define STEPBAR \
    if constexpr (DF){ \
      asm volatile("s_waitcnt lgkmcnt(0)" ::: "memory"); \
      __builtin_amdgcn_s_barrier(); \
      __builtin_amdgcn_sched_barrier(0); \
    } else { __syncthreads(); }

#define LOADA8(RBUF) \
    const char* ha = &h8s[RBUF][a8row]; \
    i32x4 a80 = *reinterpret_cast<const i32x4*>(ha + q16); \
    i32x4 a81 = *reinterpret_cast<const i32x4*>(ha + 64 + q16);

// g-gate (index 2) first: its chain retires earliest -> Eg starts early
#define GATEMM8 \
    i32x4 G2 = MI(a80, ifr[2][0], IZ); \
    i32x4 G0 = MI(a80, ifr[0][0], IZ); \
    i32x4 G1 = MI(a80, ifr[1][0], IZ); \
    i32x4 G3 = MI(a80, ifr[3][0], IZ); \
    G2 = MI(a81, ifr[2][1], G2); \
    G0 = MI(a81, ifr[0][1], G0); \
    G1 = MI(a81, ifr[1][1], G1); \
    G3 = MI(a81, ifr[3][1], G3);

// single-rcp scaled tail:
//   F = 1+ef, P = (1+ei)(Eg+1)
//   cc2' = [cc2*P + (Eg-1)*F*L2] * rcp(F*P)     (cc2 = LOG2E2 * cc)
//   Ec = exp2(clamp(cc2')); h127 = fma(Ec,127,-127)*rcp((1+eo)(Ec+1))
// i8 ds_write first (critical); history / fallback bf16 write after.
#define TAIL8(WBUF, DOHIST, HPTR, BX0L, BX1L, BX2L, BX3L) \
    float Eg = __builtin_amdgcn_exp2f(__builtin_fmaf((float)G2[0], smulL[2], BX2L)); \
    float ei = __builtin_amdgcn_exp2f(__builtin_fmaf((float)G0[0], smulL[0], BX0L)); \
    float ef = __builtin_amdgcn_exp2f(__builtin_fmaf((float)G1[0], smulL[1], BX1L)); \
    float eo = __builtin_amdgcn_exp2f(__builtin_fmaf((float)G3[0], smulL[3], BX3L)); \
    float F  = 1.0f + ef; \
    float P  = (1.0f + ei) * (Eg + 1.0f); \
    float FL2 = F * LOG2E2; \
    float T  = __builtin_fmaf(Eg, FL2, -FL2); \
    float N  = __builtin_fmaf(cc2, P, T); \
    cc2 = N * __builtin_amdgcn_rcpf(F * P); \
    float ccc = __builtin_amdgcn_fmed3f(cc2, -57.7f, 57.7f); \
    float Ec = __builtin_amdgcn_exp2f(ccc); \
    float num = __builtin_fmaf(Ec, 127.0f, -127.0f); \
    float h127 = num * __builtin_amdgcn_rcpf((1.0f + eo) * (Ec + 1.0f)); \
    h8s[WBUF][h8wofs] = (char)(int)__builtin_rintf(h127); \
    if constexpr (DF){ if (DOHIST) *(HPTR) = f2bf(h127 * INV127); } \
    else { h_lds[WBUF][hwofs] = f2bf(h127 * INV127); }

#define ENCSTEP(RBUF, WBUF, T_, DOHIST, HPTR) { \
    LOADA8(RBUF) \
    uint32 xw = *reinterpret_cast<const uint32*>(&x_lds[q * XSTR + (T_) * 2]); \
    GATEMM8 \
    /* x contribution in the scaled domain, in the MFMA-queue shadow */ \
    float xa = lo16f(xw), xb = hi16f(xw); \
    float bx0 = __builtin_fmaf(wih0L[0], xa, __builtin_fmaf(wih1L[0], xb, biasL[0])); \
    float bx1 = __builtin_fmaf(wih0L[1], xa, __builtin_fmaf(wih1L[1], xb, biasL[1])); \
    float bx2 = __builtin_fmaf(wih0L[2], xa, __builtin_fmaf(wih1L[2], xb, biasL[2])); \
    float bx3 = __builtin_fmaf(wih0L[3], xa, __builtin_fmaf(wih1L[3], xb, biasL[3])); \
    TAIL8(WBUF, DOHIST, HPTR, bx0, bx1, bx2, bx3) \
    STEPBAR \
  }

#define DECSTEP(RBUF, WBUF, D, HPTR) { \
    LOADA8(RBUF) \
    if constexpr (!DF) { \
      bf16x8 pfrag; \
      if (ispred) pfrag = *reinterpret_cast<const bf16x8*>(&h_lds[RBUF][arow] + pofs); \
      f32x4 pp; \
      if (issum && (D) > 0 && n < 2) \
        pp = *reinterpret_cast<const f32x4*>(&ppart[((D) - 1) & 1][q][n][0]); \
      GATEMM8 \
      f32x4 PP; \
      if (ispred) PP = M1(pfrag, wpfr, predC); \
      if (issum && (D) > 0 && n < 2) \
        pred_lds[q][((D) - 1) * 2 + n] = f2bf(pp[0] + pp[1] + pp[2] + pp[3]); \
      if (ispred && n < 2) ppart[(D) & 1][q][n][pkk] = PP[0]; \
      TAIL8(WBUF, 0, (ush*)0, biasL[0], biasL[1], biasL[2], biasL[3]) \
    } else { \
      GATEMM8 \
      TAIL8(WBUF, 1, HPTR, biasL[0], biasL[1], biasL[2], biasL[3]) \
    } \
    STEPBAR \
  }

  // ---------------- encoder: 256 steps + first decode cell ------------------
  #pragma unroll 1
  for (int s = 0; s < SENC; s += 2){
    ENCSTEP(0, 1, s, 0, (ush*)0)
    ENCSTEP(1, 0, s + 1, 0, (ush*)0)
  }
  ENCSTEP(0, 1, SENC - 1, 1, hlane)  // s==SENC: inp0 = x[:,-1,:]; h -> hist step 0

  // ---- decoder weight fold + re-quantize (registers/global only) ----------
  //   Whh'[g][k] = Whh[g][k] + wih0[g]*wfc[0][k] + wih1[g]*wfc[1][k]
  //   bias'[g]   = bias[g]   + wih0[g]*bfc[0]    + wih1[g]*bfc[1]
  {
    float bfc0 = loadf(bfc, 0, isf32), bfc1 = loadf(bfc, 1, isf32);
    #pragma unroll
    for (int p = 0; p < 4; ++p){
      const float cf = (p == 0) ? coef0 : (p == 1) ? coef1 : (p == 2) ? coef2 : coef3;
      int g = p * 128 + gbase + n;
      biasv[p] = biasv[p] + wih0v[p] * bfc0 + wih1v[p] * bfc1;
      float w[2][16]; float m = 0.0f;
      #pragma unroll
      for (int kh = 0; kh < 2; ++kh){
        #pragma unroll
        for (int j = 0; j < 16; ++j){
          int k = kh * 64 + q16 + j;
          float v = loadf(whh, g * HDIM + k, isf32)
                  + wih0v[p] * loadf(wfc, k, isf32)
                  + wih1v[p] * loadf(wfc, HDIM + k, isf32);
          w[kh][j] = v; m = __builtin_fmaxf(m, __builtin_fabsf(v));
        }
      }
      m = __builtin_fmaxf(m, __shfl_xor(m, 16, 64));
      m = __builtin_fmaxf(m, __shfl_xor(m, 32, 64));
      m = __builtin_fmaxf(m, 1e-20f);
      float sinv = 127.0f / m;
      smulL[p] = cf * m * (1.0f / (127.0f * 127.0f));
      biasL[p] = cf * biasv[p];
      #pragma unroll
      for (int kh = 0; kh < 2; ++kh){
        c8x16 c;
        #pragma unroll
        for (int j = 0; j < 16; ++j)
          c[j] = (char)(int)__builtin_rintf(w[kh][j] * sinv);
        ifr[p][kh] = __builtin_bit_cast(i32x4, c);
      }
    }
  }

  // ---------------- decoder: pure h-recurrence (folded i8 weights) ----------
  // unroll x4; history base bumped once per group, stores at immediate offsets
  #pragma unroll 1
  for (int d = 0; d < TDEC - 4; d += 4){
    ush* hb = hlane + (d + 1) * 512;
    DECSTEP(1, 0, d,     hb)
    DECSTEP(0, 1, d + 1, hb + 512)
    DECSTEP(1, 0, d + 2, hb + 1024)
    DECSTEP(0, 1, d + 3, hb + 1536)
  }
  {
    ush* hb = hlane + (TDEC - 3) * 512;
    DECSTEP(1, 0, TDEC - 4, hb)        // d==508
    DECSTEP(0, 1, TDEC - 3, hb + 512)  // d==509
    DECSTEP(1, 0, TDEC - 2, hb + 1024) // d==510; final h -> hist step 511
  }

  if constexpr (DF){
    // ---- deferred pred: per-block GEMM over own history -------------------
    // single drain of ALL history stores, then block-wide visibility
    asm volatile("s_waitcnt vmcnt(0)" ::: "memory");
    __syncthreads();

    // column-replicated wfc frags + bias (all waves)
    bf16x8 wfe[4];
    #pragma unroll
    for (int kk = 0; kk < 4; ++kk)
      #pragma unroll
      for (int j = 0; j < 8; ++j)
        wfe[kk][j] = (__bf16)loadf(wfc, (n & 1) * HDIM + kk * 32 + q8 + j, isf32);
    f32x4 predCe;
    {
      float pb = loadf(bfc, n & 1, isf32);
      predCe[0] = pb; predCe[1] = pb; predCe[2] = pb; predCe[3] = pb;
    }
    const ush* hg = (const ush*)ws + (((size_t)blk) << 18);
    // M = 2048 (step*4+row), 128 tiles of 16; wave wv owns tiles wv*16..+15
    #pragma unroll 4
    for (int i = 0; i < 16; ++i){
      int t = wv * 16 + i;
      const ush* ar = hg + ((t * 16 + n) << 7) + q8;  // A[m=16t+n][k=q8+...]
      bf16x8 a0 = __builtin_bit_cast(bf16x8, *reinterpret_cast<const uint4*>(ar));
      bf16x8 a1 = __builtin_bit_cast(bf16x8, *reinterpret_cast<const uint4*>(ar + 32));
      bf16x8 a2 = __builtin_bit_cast(bf16x8, *reinterpret_cast<const uint4*>(ar + 64));
      bf16x8 a3 = __builtin_bit_cast(bf16x8, *reinterpret_cast<const uint4*>(ar + 96));
      f32x4 P = M1(a0, wfe[0], predCe);
      P = M1(a1, wfe[1], P);
      P = M1(a2, wfe[2], P);
      P = M1(a3, wfe[3], P);
      #pragma unroll
      for (int r = 0; r < 4; ++r){
        int m = t * 16 + 4 * q + r;     // (step = m>>2, row = m&3)
        pred_lds[m & 3][((m >> 2) << 1) + (n & 1)] = f2bf(P[r]);
      }
    }
  } else {
    // pending pred sum for d == TDEC-2 (buffer (TDEC-2)&1 == 0)
    if (issum && n < 2){
      f32x4 pp = *reinterpret_cast<const f32x4*>(&ppart[0][q][n][0]);
      pred_lds[q][(TDEC - 2) * 2 + n] = f2bf(pp[0] + pp[1] + pp[2] + pp[3]);
    }
    // epilogue: pred_511 from final h (buf0, bf16 copy), wave 0 full chain
    if (wv == 0){
      const ush* hb = &h_lds[0][arow];
      bf16x8 af0 = *reinterpret_cast<const bf16x8*>(hb + q8);
      bf16x8 af2 = *reinterpret_cast<const bf16x8*>(hb + 64 + q8);
      bf16x8 af1 = *reinterpret_cast<const bf16x8*>(hb + 32 + q8);
      bf16x8 af3 = *reinterpret_cast<const bf16x8*>(hb + 96 + q8);
      bf16x8 wf0, wf1, wf2, wf3;
      #pragma unroll
      for (int j = 0; j < 8; ++j){
        wf0[j] = (__bf16)loadf(wfc, (n & 1) * HDIM +   0 + q8 + j, isf32);
        wf1[j] = (__bf16)loadf(wfc, (n & 1) * HDIM +  32 + q8 + j, isf32);
        wf2[j] = (__bf16)loadf(wfc, (n & 1) * HDIM +  64 + q8 + j, isf32);
        wf3[j] = (__bf16)loadf(wfc, (n & 1) * HDIM +  96 + q8 + j, isf32);
      }
      f32x4 P = M1(af0, wf0, predC);
      f32x4 Q = M1(af2, wf2, Z);
      P = M1(af1, wf1, P);
      Q = M1(af3, wf3, Q);
      if (n < 2)
        pred_lds[q][(TDEC - 1) * 2 + n] = f2bf(P[0] + Q[0]);
    }
  }
  __syncthreads();

  // bulk coalesced output write: 4 rows x 1024 ush per block
  if (!isf32){
    int row = tid >> 7, c = (tid & 127) * 8;  // 512 threads x uint4
    uint4 v = *reinterpret_cast<const uint4*>(&pred_lds[row][c]);
    *reinterpret_cast<uint4*>((ush*)outg + (blk * RB + row) * (TDEC * 2) + c) = v;
  } else {
    for (int i = tid; i < RB * TDEC * 2; i += NTHR){
      int row = i >> 10, c = i & 1023;
      ((float*)outg)[(blk * RB + row) * (TDEC * 2) + c] = bf2f(pred_lds[row][c]);
    }
  }
}

extern "C" void kernel_launch(void* const* d_in, const int* in_sizes, int n_in,
                              void* d_out, int out_size, void* d_ws, size_t ws_size,
                              hipStream_t stream) {
  const bool defer = (d_ws != nullptr) && (ws_size >= WS_NEEDED);
  if (defer){
    lstm_kernel<true><<<dim3(NBLK), dim3(NTHR), 0, stream>>>(
        d_in[0], d_in[1], d_in[2], d_in[3], d_in[4], d_in[5], d_in[6], d_out, d_ws);
  } else {
    lstm_kernel<false><<<dim3(NBLK), dim3(NTHR), 0, stream>>>(
        d_in[0], d_in[1], d_in[2], d_in[3], d_in[4], d_in[5], d_in[6], d_out, d_ws);
  }
}